// Round 15
// baseline (467.160 us; speedup 1.0000x reference)
//
#include <hip/hip_runtime.h>
#include <hip/hip_bf16.h>

#define DIM 64
#define NREL 8
#define KS 512              // Sx width (k-permuted: k = ch*8 + r)
#define KTOT 576            // GEMM K: 512 + 64 root
#define PADK 520            // LDS row stride in bf16 (1040B) -> uniform bank spread

typedef __bf16 bf16x8 __attribute__((ext_vector_type(8)));
typedef __bf16 bf16x4 __attribute__((ext_vector_type(4)));
typedef float  f32x4  __attribute__((ext_vector_type(4)));

// ---------------- fused: hist (rank-returning) + initial gather (vectorized) + sentinels ----
__global__ __launch_bounds__(256) void histgather_kernel(const int* __restrict__ dst,
                                                         const int* __restrict__ et,
                                                         int* __restrict__ deg8,
                                                         int* __restrict__ eoff,
                                                         const int* __restrict__ x_idx,
                                                         const float* __restrict__ emb,
                                                         __bf16* __restrict__ xb0,
                                                         __bf16* __restrict__ xb1,
                                                         int* __restrict__ srcs,
                                                         int N, int E, int epad_cap) {
    int i = blockIdx.x * 256 + threadIdx.x;
    if (i < N * (DIM / 8)) {                              // vectorized gather-copy (8 elem/thr)
        int n = i >> 3;
        int c0 = (i & 7) * 8;
        const float* ep = emb + (size_t)x_idx[n] * DIM + c0;
        f32x4 e0 = *reinterpret_cast<const f32x4*>(ep);
        f32x4 e1 = *reinterpret_cast<const f32x4*>(ep + 4);
        bf16x8 v;
#pragma unroll
        for (int j = 0; j < 4; ++j) { v[j] = (__bf16)e0[j]; v[4 + j] = (__bf16)e1[j]; }
        *reinterpret_cast<bf16x8*>(xb0 + (size_t)n * DIM + c0) = v;
    }
    if (i < DIM) {                                        // sentinel zero rows (node index N)
        xb0[(size_t)N * DIM + i] = (__bf16)0.f;
        xb1[(size_t)N * DIM + i] = (__bf16)0.f;
    }
    if (i < epad_cap) srcs[i] = N;                        // padding -> sentinel src
    if (i < E) eoff[i] = atomicAdd(&deg8[dst[i] * 8 + et[i]], 1);  // rank within (dst,rel) cell
}

// ---------------- scan1rp: scan1 + GLOBAL base via atomicAdd + rp/rend build + wcat ------
// wcat emits R3 layout: Wt[l][c][k]; k<512 -> k=ch*8+r maps weight[l][r][ch][c];
//                        k>=512 -> root[l][k-512][c]
__global__ __launch_bounds__(256) void scan1rp_kernel(const int* __restrict__ deg8,
                                                      int* __restrict__ gtotal,
                                                      float* __restrict__ invdeg,
                                                      int* __restrict__ rp,
                                                      int* __restrict__ rend,
                                                      const float* __restrict__ weight,
                                                      const float* __restrict__ root,
                                                      __bf16* __restrict__ Wt,
                                                      int N, int L) {
    __shared__ int sd[256];
    __shared__ int sbase;
    int tid = threadIdx.x;
    int d = blockIdx.x * 256 + tid;
    int dv[NREL];
    int vpad = 0;
    if (d < N) {
        int vtrue = 0;
#pragma unroll
        for (int r = 0; r < NREL; ++r) { dv[r] = deg8[d * 8 + r]; vtrue += dv[r]; }
        vpad = (vtrue + 3) & ~3;                          // pad per ROW
        invdeg[d] = 1.0f / fmaxf((float)vtrue, 1.0f);
    }
    sd[tid] = vpad;
    __syncthreads();
#pragma unroll
    for (int off = 1; off < 256; off <<= 1) {             // inclusive block scan
        int t = (tid >= off) ? sd[tid - off] : 0;
        __syncthreads();
        sd[tid] += t;
        __syncthreads();
    }
    if (tid == 255) sbase = atomicAdd(gtotal, sd[255]);   // claim block's global range
    __syncthreads();
    if (d < N) {
        int base = sbase + sd[tid] - vpad;                // exclusive within block
        int run = 0;
#pragma unroll
        for (int r = 0; r < NREL; ++r) {
            rp[d * 8 + r] = base + run;
            run += dv[r];                                 // exact (no per-cell pad)
        }
        rend[d] = base + vpad;                            // padded row end
    }
    // ---- wcat tail (R3 k-permuted layout) ----
    int total = L * 64 * KTOT;
    for (int idx = blockIdx.x * 256 + tid; idx < total; idx += gridDim.x * 256) {
        int l = idx / (64 * KTOT);
        int rem = idx - l * 64 * KTOT;
        int c = rem / KTOT;
        int k = rem - c * KTOT;
        float w;
        if (k < KS) {
            int ch = k >> 3, r = k & 7;
            w = weight[(((l * 8 + r) * 64) + ch) * 64 + c];
        } else {
            w = root[(l * 64 + (k - KS)) * 64 + c];
        }
        Wt[idx] = (__bf16)w;
    }
}

// ---------------- bucket: atomic-free scatter of PLAIN src index ----------------
__global__ __launch_bounds__(256) void bucket_kernel(const int* __restrict__ src,
                                                     const int* __restrict__ dst,
                                                     const int* __restrict__ et,
                                                     const int* __restrict__ rp,
                                                     const int* __restrict__ eoff,
                                                     int* __restrict__ srcs, int E) {
    int i = blockIdx.x * 256 + threadIdx.x;
    int half = (E + 1) >> 1;
    if (i >= half) return;
    int iB = i + half;
    bool hasB = iB < E;
    int cellA = dst[i] * 8 + et[i];
    int cellB = hasB ? dst[iB] * 8 + et[iB] : 0;
    int rA = rp[cellA];
    int rB = hasB ? rp[cellB] : 0;
    int oA = eoff[i];
    int oB = hasB ? eoff[iB] : 0;
    int sA = src[i];
    int sB = hasB ? src[iB] : 0;
    srcs[rA + oA] = sA;                                   // plain src (rel implied by position)
    if (hasB) srcs[rB + oB] = sB;
}

// scalar 8-way flush of running acc into named per-rel accumulators (rel is wave-uniform)
#define FLUSH()  do { switch (rel) {                                          \
    case 0: f0 += acc; break; case 1: f1 += acc; break;                       \
    case 2: f2 += acc; break; case 3: f3 += acc; break;                       \
    case 4: f4 += acc; break; case 5: f5 += acc; break;                       \
    case 6: f6 += acc; break; default: f7 += acc; break; } acc = 0.f; } while (0)

// slot qj's rel is monotone; advance (rare, scalar) then accumulate (vector, branch-free)
#define STEP(J, VJ) { int qj = q + (J);                                       \
    while (rel < 7 && qj >= rpv[rel + 1]) { FLUSH(); ++rel; }                 \
    acc += (VJ); }

// ---------------- aggemm3: segmented x-direct aggregation + fused rel/root GEMM ----------
// Slots within a row are rel-sorted (cell starts in rp) and q+J is SCALAR -> each slot's
// rel is wave-uniform + monotone. One running register acc, flushed at cell boundaries
// (~6.5 scalar branches/row, NOT per slot) -> 16 gathers stay batched (fixes R3/R8).
// Gathers hit x (12.8MB, part-L2) instead of hbuf (102MB, pure-L3); transform+hbuf deleted.
// xout MUST NOT alias xin (gathers read other nodes' rows while xnxt is written).
__global__ __launch_bounds__(256) void aggemm3_kernel(const __bf16* __restrict__ xb,
                                                      const int* __restrict__ srcs,
                                                      const int* __restrict__ rp,
                                                      const int* __restrict__ rend,
                                                      const float* __restrict__ invdeg,
                                                      const __bf16* __restrict__ Wt,    // [64][576]
                                                      const float* __restrict__ bias_l, // [64]
                                                      __bf16* __restrict__ xout, int N) {
    __shared__ __align__(16) __bf16 S[16 * PADK];
    int wave = threadIdx.x >> 6;
    int lane = threadIdx.x & 63;
    int l15 = lane & 15;
    int lg  = lane >> 4;

    // hoist A (weights) into registers once per block: 18 x 4 VGPRs = 72 VGPRs
    bf16x8 afrag[KTOT / 32];
    {
        const __bf16* wrow = Wt + (size_t)(16 * wave + l15) * KTOT + lg * 8;
#pragma unroll
        for (int kk = 0; kk < KTOT / 32; ++kk)
            afrag[kk] = *reinterpret_cast<const bf16x8*>(wrow + kk * 32);
    }
    int cbase = 16 * wave + 4 * lg;
    f32x4 bias4 = *reinterpret_cast<const f32x4*>(bias_l + cbase);

    int ntiles = (N + 15) >> 4;
    for (int tile = blockIdx.x; tile < ntiles; tile += gridDim.x) {
        // ---------- phase A: segmented aggregation, 4 rows per wave ----------
#pragma unroll
        for (int rr = 0; rr < 4; ++rr) {
            int d0 = tile * 16 + wave * 4 + rr;
            if (d0 >= N) d0 = N - 1;                      // tail tile only
            int d = __builtin_amdgcn_readfirstlane(d0);
            int rpv[9];
#pragma unroll
            for (int r = 0; r < 8; ++r) rpv[r] = rp[d * 8 + r];   // uniform scalar loads
            rpv[8] = rend[d];                             // padded row end
            float f0 = 0.f, f1 = 0.f, f2 = 0.f, f3 = 0.f;
            float f4 = 0.f, f5 = 0.f, f6 = 0.f, f7 = 0.f;
            float acc = 0.f;
            int rel = 0;
            for (int q = rpv[0]; q < rpv[8]; q += 16) {
                int rem = rpv[8] - q;                     // multiple of 4, >= 4
                int4 sa = *reinterpret_cast<const int4*>(srcs + q);       // scalar dwordx4
                int4 sb = *reinterpret_cast<const int4*>(srcs + q + 4);
                int4 sc = *reinterpret_cast<const int4*>(srcs + q + 8);
                int4 sd = *reinterpret_cast<const int4*>(srcs + q + 12);
                bool vb = rem >= 8, vc = rem >= 12, vd = rem >= 16;
                int i0 = sa.x,            i1 = sa.y,            i2 = sa.z,            i3 = sa.w;
                int i4 = vb ? sb.x : N,   i5 = vb ? sb.y : N,   i6 = vb ? sb.z : N,   i7 = vb ? sb.w : N;
                int i8 = vc ? sc.x : N,   i9 = vc ? sc.y : N,   iA = vc ? sc.z : N,   iB = vc ? sc.w : N;
                int iC = vd ? sd.x : N,   iD = vd ? sd.y : N,   iE = vd ? sd.z : N,   iF = vd ? sd.w : N;
                // 16 independent gathers, issued before any consumption (batched MLP)
                float v0 = (float)xb[(size_t)i0 * DIM + lane];
                float v1 = (float)xb[(size_t)i1 * DIM + lane];
                float v2 = (float)xb[(size_t)i2 * DIM + lane];
                float v3 = (float)xb[(size_t)i3 * DIM + lane];
                float v4 = (float)xb[(size_t)i4 * DIM + lane];
                float v5 = (float)xb[(size_t)i5 * DIM + lane];
                float v6 = (float)xb[(size_t)i6 * DIM + lane];
                float v7 = (float)xb[(size_t)i7 * DIM + lane];
                float v8 = (float)xb[(size_t)i8 * DIM + lane];
                float v9 = (float)xb[(size_t)i9 * DIM + lane];
                float vA = (float)xb[(size_t)iA * DIM + lane];
                float vB = (float)xb[(size_t)iB * DIM + lane];
                float vC = (float)xb[(size_t)iC * DIM + lane];
                float vD = (float)xb[(size_t)iD * DIM + lane];
                float vE = (float)xb[(size_t)iE * DIM + lane];
                float vF = (float)xb[(size_t)iF * DIM + lane];
                // sequential segmented accumulate (vector adds; rare scalar flushes)
                STEP(0, v0);  STEP(1, v1);  STEP(2, v2);  STEP(3, v3);
                STEP(4, v4);  STEP(5, v5);  STEP(6, v6);  STEP(7, v7);
                STEP(8, v8);  STEP(9, v9);  STEP(10, vA); STEP(11, vB);
                STEP(12, vC); STEP(13, vD); STEP(14, vE); STEP(15, vF);
            }
            FLUSH();                                      // final cell
            float inv = invdeg[d];
            bf16x8 h;
            h[0] = (__bf16)(f0 * inv); h[1] = (__bf16)(f1 * inv);
            h[2] = (__bf16)(f2 * inv); h[3] = (__bf16)(f3 * inv);
            h[4] = (__bf16)(f4 * inv); h[5] = (__bf16)(f5 * inv);
            h[6] = (__bf16)(f6 * inv); h[7] = (__bf16)(f7 * inv);
            // k-permuted row: element k = ch*8 + r, lane holds ch=lane -> 16B contiguous
            *reinterpret_cast<bf16x8*>(&S[(wave * 4 + rr) * PADK + lane * 8]) = h;
        }
        __syncthreads();

        // ---------- phase B: 16x64 GEMM over K=576 (R3-verified) ----------
        int n = tile * 16 + l15;
        int nc = (n < N) ? n : (N - 1);                   // clamped load, guarded store
        const __bf16* xrow = xb + (size_t)nc * DIM + lg * 8;
        const __bf16* srow = &S[l15 * PADK + lg * 8];

        f32x4 acc2 = (f32x4){0.f, 0.f, 0.f, 0.f};
#pragma unroll
        for (int kk = 0; kk < KS / 32; ++kk) {
            bf16x8 bv = *reinterpret_cast<const bf16x8*>(srow + kk * 32);
            acc2 = __builtin_amdgcn_mfma_f32_16x16x32_bf16(afrag[kk], bv, acc2, 0, 0, 0);
        }
#pragma unroll
        for (int kk = 0; kk < DIM / 32; ++kk) {
            bf16x8 bv = *reinterpret_cast<const bf16x8*>(xrow + kk * 32);
            acc2 = __builtin_amdgcn_mfma_f32_16x16x32_bf16(afrag[KS / 32 + kk], bv, acc2, 0, 0, 0);
        }

        if (n < N) {
            bf16x4 h;
#pragma unroll
            for (int i = 0; i < 4; ++i)
                h[i] = (__bf16)fmaxf(acc2[i] + bias4[i], 0.f);
            *reinterpret_cast<bf16x4*>(xout + (size_t)n * DIM + cbase) = h;
        }
        __syncthreads();                                  // WAR: next tile rewrites S
    }
}

// ---------------- score ----------------
__global__ __launch_bounds__(256) void score_kernel(const __bf16* __restrict__ xb,
                                                    const int* __restrict__ s,
                                                    const int* __restrict__ t,
                                                    float* __restrict__ out, int T) {
    int i = blockIdx.x * 4 + (threadIdx.x >> 6);
    if (i >= T) return;
    int lane = threadIdx.x & 63;
    float p = (float)xb[(size_t)s[i] * DIM + lane] * (float)xb[(size_t)t[i] * DIM + lane];
#pragma unroll
    for (int off = 32; off > 0; off >>= 1) p += __shfl_down(p, off, 64);
    if (lane == 0) out[i] = p;
}

extern "C" void kernel_launch(void* const* d_in, const int* in_sizes, int n_in,
                              void* d_out, int out_size, void* d_ws, size_t ws_size,
                              hipStream_t stream) {
    const int*   x_idx  = (const int*)d_in[0];
    const int*   eidx   = (const int*)d_in[1];   // [2,E]
    const int*   etyp   = (const int*)d_in[2];   // [E]
    const int*   tidx   = (const int*)d_in[3];   // [2,T]
    const float* emb    = (const float*)d_in[4]; // [N,64]
    const float* weight = (const float*)d_in[5]; // [L,8,64,64]
    const float* root   = (const float*)d_in[6]; // [L,64,64]
    const float* bias   = (const float*)d_in[7]; // [L,64]

    int N = in_sizes[0];
    int E = in_sizes[2];
    int T = in_sizes[3] / 2;
    int L = in_sizes[5] / (NREL * DIM * DIM);

    const int* src = eidx;
    const int* dst = eidx + E;
    const int* ts  = tidx;
    const int* tt  = tidx + T;
    float* out = (float*)d_out;

    int epad_cap = E + 3 * N + 64;              // per-row pad <= 3, + 16-deep over-read slack

    // ---- workspace carve-up ----
    char* p = (char*)d_ws;
    auto alloc = [&](size_t bytes) -> void* {
        void* r = (void*)p;
        p += (bytes + 255) & ~(size_t)255;
        return r;
    };
    __bf16* xb0     = (__bf16*)alloc((size_t)(N + 1) * DIM * sizeof(__bf16));  // +1 zero row
    __bf16* xb1     = (__bf16*)alloc((size_t)(N + 1) * DIM * sizeof(__bf16));  // ping-pong
    __bf16* Wt      = (__bf16*)alloc((size_t)L * 64 * KTOT * sizeof(__bf16));
    int*    srcs    = (int*)   alloc((size_t)epad_cap * sizeof(int));
    int*    eoff    = (int*)   alloc((size_t)E * sizeof(int));
    int*    deg8    = (int*)   alloc(((size_t)N * 8 + 8) * sizeof(int));  // +8: gtotal at [N*8]
    int*    rp      = (int*)   alloc((size_t)N * 8 * sizeof(int));
    int*    rend    = (int*)   alloc((size_t)N * sizeof(int));
    float*  invdeg  = (float*) alloc((size_t)N * sizeof(float));

    int* gtotal = deg8 + (size_t)N * 8;         // zeroed by the same memset

    int nb = (N + 255) / 256;

    hipMemsetAsync(deg8, 0, ((size_t)N * 8 + 8) * sizeof(int), stream);
    {   // grid must cover max(epad_cap, E, N*DIM/8, DIM)
        int work = epad_cap;
        if (E > work) work = E;
        int copyw = N * (DIM / 8);
        if (copyw > work) work = copyw;
        histgather_kernel<<<(work + 255) / 256, 256, 0, stream>>>(
            dst, etyp, deg8, eoff, x_idx, emb, xb0, xb1, srcs, N, E, epad_cap);
    }
    scan1rp_kernel<<<nb, 256, 0, stream>>>(deg8, gtotal, invdeg, rp, rend,
                                           weight, root, Wt, N, L);
    {
        int half = (E + 1) / 2;
        bucket_kernel<<<(half + 255) / 256, 256, 0, stream>>>(src, dst, etyp, rp, eoff, srcs, E);
    }

    __bf16* xcur = xb0;
    __bf16* xnxt = xb1;
    for (int l = 0; l < L; ++l) {
        aggemm3_kernel<<<2048, 256, 0, stream>>>(xcur, srcs, rp, rend, invdeg,
                                                 Wt + (size_t)l * 64 * KTOT,
                                                 bias + (size_t)l * DIM,
                                                 xnxt, N);
        __bf16* tmp = xcur; xcur = xnxt; xnxt = tmp;
    }

    score_kernel<<<(T + 3) / 4, 256, 0, stream>>>(xcur, ts, tt, out, T);
}

// Round 16
// 357.310 us; speedup vs baseline: 1.3074x; 1.3074x over previous
//
#include <hip/hip_runtime.h>
#include <hip/hip_bf16.h>

#define DIM 64
#define NREL 8
#define KTOT 576            // Wt2 rows: 512 rel-cols + 64 root cols

typedef __bf16 bf16x8 __attribute__((ext_vector_type(8)));
typedef __bf16 bf16x4 __attribute__((ext_vector_type(4)));
typedef float  f32x4  __attribute__((ext_vector_type(4)));

// ---------------- fused: hist (rank-returning) + initial gather (VECTORIZED) + sentinels ----
// Copy path: 8 elems/thread (2x float4 -> bf16x8); atomics unchanged (1 per edge).
// histgather is atomic-transaction-rate-bound (R14: VALUBusy 4.3->1.25%, dur unchanged).
__global__ __launch_bounds__(256) void histgather_kernel(const int* __restrict__ dst,
                                                         const int* __restrict__ et,
                                                         int* __restrict__ deg8,
                                                         int* __restrict__ eoff,
                                                         const int* __restrict__ x_idx,
                                                         const float* __restrict__ emb,
                                                         __bf16* __restrict__ xb0,
                                                         __bf16* __restrict__ hbuf,
                                                         int* __restrict__ srcs,
                                                         int N, int E, int epad_cap) {
    int i = blockIdx.x * 256 + threadIdx.x;
    if (i < N * (DIM / 8)) {                              // vectorized gather-copy
        int n = i >> 3;
        int c0 = (i & 7) * 8;
        const float* ep = emb + (size_t)x_idx[n] * DIM + c0;
        f32x4 e0 = *reinterpret_cast<const f32x4*>(ep);
        f32x4 e1 = *reinterpret_cast<const f32x4*>(ep + 4);
        bf16x8 v;
#pragma unroll
        for (int j = 0; j < 4; ++j) { v[j] = (__bf16)e0[j]; v[4 + j] = (__bf16)e1[j]; }
        *reinterpret_cast<bf16x8*>(xb0 + (size_t)n * DIM + c0) = v;
    }
    if (i < DIM) {                                        // sentinel zero row in h (gidx = 8N)
        hbuf[(size_t)N * NREL * DIM + i] = (__bf16)0.f;
    }
    if (i < epad_cap) srcs[i] = N * NREL;                 // padding -> sentinel gidx
    if (i < E) eoff[i] = atomicAdd(&deg8[dst[i] * 8 + et[i]], 1);  // rank within (dst,rel) cell
}

// ---------------- scan1rp: scan1 + GLOBAL base via atomicAdd + rp/rend build + wcat ------
__global__ __launch_bounds__(256) void scan1rp_kernel(const int* __restrict__ deg8,
                                                      int* __restrict__ gtotal,
                                                      float* __restrict__ invdeg,
                                                      int* __restrict__ rp,
                                                      int* __restrict__ rend,
                                                      const float* __restrict__ weight,
                                                      const float* __restrict__ root,
                                                      __bf16* __restrict__ Wt2,
                                                      int N, int L) {
    __shared__ int sd[256];
    __shared__ int sbase;
    int tid = threadIdx.x;
    int d = blockIdx.x * 256 + tid;
    int dv[NREL];
    int vpad = 0;
    if (d < N) {
        int vtrue = 0;
#pragma unroll
        for (int r = 0; r < NREL; ++r) { dv[r] = deg8[d * 8 + r]; vtrue += dv[r]; }
        vpad = (vtrue + 3) & ~3;                          // pad per ROW
        invdeg[d] = 1.0f / fmaxf((float)vtrue, 1.0f);
    }
    sd[tid] = vpad;
    __syncthreads();
#pragma unroll
    for (int off = 1; off < 256; off <<= 1) {             // inclusive block scan
        int t = (tid >= off) ? sd[tid - off] : 0;
        __syncthreads();
        sd[tid] += t;
        __syncthreads();
    }
    if (tid == 255) sbase = atomicAdd(gtotal, sd[255]);   // claim block's global range
    __syncthreads();
    if (d < N) {
        int base = sbase + sd[tid] - vpad;                // exclusive within block
        int run = 0;
#pragma unroll
        for (int r = 0; r < NREL; ++r) {
            rp[d * 8 + r] = base + run;
            run += dv[r];                                 // exact (no per-cell pad)
        }
        rend[d] = base + vpad;                            // padded row end
    }
    // ---- wcat tail ----
    int total = L * KTOT * DIM;
    for (int idx = blockIdx.x * 256 + tid; idx < total; idx += gridDim.x * 256) {
        int l = idx / (KTOT * DIM);
        int rem = idx - l * (KTOT * DIM);
        int row = rem / DIM;
        int ch = rem - row * DIM;
        float w;
        if (row < 512) {
            int r = row >> 6, c = row & 63;
            w = weight[(((l * 8 + r) * 64) + ch) * 64 + c];
        } else {
            w = root[(l * 64 + ch) * 64 + (row - 512)];
        }
        Wt2[idx] = (__bf16)w;
    }
}

// ---------------- bucket: atomic-free scatter of PACKED gather index src*8+rel ----------------
__global__ __launch_bounds__(256) void bucket_kernel(const int* __restrict__ src,
                                                     const int* __restrict__ dst,
                                                     const int* __restrict__ et,
                                                     const int* __restrict__ rp,
                                                     const int* __restrict__ eoff,
                                                     int* __restrict__ srcs, int E) {
    int i = blockIdx.x * 256 + threadIdx.x;
    int half = (E + 1) >> 1;
    if (i >= half) return;
    int iB = i + half;
    bool hasB = iB < E;
    int etA = et[i];
    int etB = hasB ? et[iB] : 0;
    int cellA = dst[i] * 8 + etA;
    int cellB = hasB ? dst[iB] * 8 + etB : 0;
    int rA = rp[cellA];
    int rB = hasB ? rp[cellB] : 0;
    int oA = eoff[i];
    int oB = hasB ? eoff[iB] : 0;
    int sA = src[i];
    int sB = hasB ? src[iB] : 0;
    srcs[rA + oA] = sA * NREL + etA;                      // packed gidx
    if (hasB) srcs[rB + oB] = sB * NREL + etB;
}

// ---------------- transform: grid-stride over 16-node tiles; afrag hoisted once ----------------
__global__ __launch_bounds__(256) void transform_kernel(const __bf16* __restrict__ xin,
                                                        const __bf16* __restrict__ Wt2,  // [576][64]
                                                        __bf16* __restrict__ h, int N) {
    int wave = threadIdx.x >> 6;
    int lane = threadIdx.x & 63;
    int l15 = lane & 15;
    int lg  = lane >> 4;

    bf16x8 afrag[8][2];
#pragma unroll
    for (int p = 0; p < 8; ++p) {
        const __bf16* wrow = Wt2 + (size_t)(p * 64 + 16 * wave + l15) * DIM + lg * 8;
        afrag[p][0] = *reinterpret_cast<const bf16x8*>(wrow);
        afrag[p][1] = *reinterpret_cast<const bf16x8*>(wrow + 32);
    }
    int cb = 16 * wave + 4 * lg;

    int ntiles = (N + 15) >> 4;
    for (int tile = blockIdx.x; tile < ntiles; tile += gridDim.x) {
        int n = tile * 16 + l15;
        int nc = (n < N) ? n : (N - 1);
        const __bf16* xrow = xin + (size_t)nc * DIM + lg * 8;
        bf16x8 bv0 = *reinterpret_cast<const bf16x8*>(xrow);
        bf16x8 bv1 = *reinterpret_cast<const bf16x8*>(xrow + 32);

#pragma unroll
        for (int p = 0; p < 8; ++p) {
            f32x4 acc = (f32x4){0.f, 0.f, 0.f, 0.f};
            acc = __builtin_amdgcn_mfma_f32_16x16x32_bf16(afrag[p][0], bv0, acc, 0, 0, 0);
            acc = __builtin_amdgcn_mfma_f32_16x16x32_bf16(afrag[p][1], bv1, acc, 0, 0, 0);
            if (n < N) {
                bf16x4 hv;
#pragma unroll
                for (int i = 0; i < 4; ++i) hv[i] = (__bf16)acc[i];
                *reinterpret_cast<bf16x4*>(h + (size_t)n * (NREL * DIM) + p * 64 + cb) = hv;
            }
        }
    }
}

// ---------------- aggroot (R11-verified): 16-deep masked gathers + root GEMM epilogue ----------
__global__ __launch_bounds__(256) void aggroot_kernel(const __bf16* __restrict__ h,
                                                      const __bf16* __restrict__ xin,
                                                      const int* __restrict__ srcs,
                                                      const int* __restrict__ rp,
                                                      const int* __restrict__ rend,
                                                      const float* __restrict__ invdeg,
                                                      const __bf16* __restrict__ Wt2,   // rows 512..575
                                                      const float* __restrict__ bias_l, // [64]
                                                      __bf16* __restrict__ xout, int N) {
    __shared__ __align__(16) float S16[16][68];           // 68: pad -> conflict-free epilogue reads
    int wave = threadIdx.x >> 6;
    int lane = threadIdx.x & 63;
    int l15 = lane & 15;
    int lg  = lane >> 4;
    const int SENT = N * NREL;                            // sentinel gidx (zero row)

    bf16x8 ar0, ar1;
    {
        const __bf16* wrow = Wt2 + (size_t)(512 + 16 * wave + l15) * DIM + lg * 8;
        ar0 = *reinterpret_cast<const bf16x8*>(wrow);
        ar1 = *reinterpret_cast<const bf16x8*>(wrow + 32);
    }
    int cbase = 16 * wave + 4 * lg;
    f32x4 bias4 = *reinterpret_cast<const f32x4*>(bias_l + cbase);

    int tile = blockIdx.x;

    // ---------- phase A: 4 rows per wave, 16 gathers in flight ----------
#pragma unroll
    for (int rr = 0; rr < 4; ++rr) {
        int d0 = tile * 16 + wave * 4 + rr;
        if (d0 >= N) d0 = N - 1;                          // tail tile only
        int d = __builtin_amdgcn_readfirstlane(d0);
        int qb = rp[d * 8];
        int qe = rend[d];                                 // padded row end
        float acc = 0.f;
        for (int q = qb; q < qe; q += 16) {
            int rem = qe - q;                             // multiple of 4, >= 4
            int4 sa = *reinterpret_cast<const int4*>(srcs + q);
            int4 sb = *reinterpret_cast<const int4*>(srcs + q + 4);
            int4 sc = *reinterpret_cast<const int4*>(srcs + q + 8);
            int4 sd = *reinterpret_cast<const int4*>(srcs + q + 12);
            bool vb = rem >= 8, vc = rem >= 12, vd = rem >= 16;
            int i0 = sa.x,              i1 = sa.y,              i2 = sa.z,              i3 = sa.w;
            int i4 = vb ? sb.x : SENT,  i5 = vb ? sb.y : SENT,  i6 = vb ? sb.z : SENT,  i7 = vb ? sb.w : SENT;
            int i8 = vc ? sc.x : SENT,  i9 = vc ? sc.y : SENT,  iA = vc ? sc.z : SENT,  iB = vc ? sc.w : SENT;
            int iC = vd ? sd.x : SENT,  iD = vd ? sd.y : SENT,  iE = vd ? sd.z : SENT,  iF = vd ? sd.w : SENT;
            float v0 = (float)h[(size_t)i0 * DIM + lane];
            float v1 = (float)h[(size_t)i1 * DIM + lane];
            float v2 = (float)h[(size_t)i2 * DIM + lane];
            float v3 = (float)h[(size_t)i3 * DIM + lane];
            float v4 = (float)h[(size_t)i4 * DIM + lane];
            float v5 = (float)h[(size_t)i5 * DIM + lane];
            float v6 = (float)h[(size_t)i6 * DIM + lane];
            float v7 = (float)h[(size_t)i7 * DIM + lane];
            float v8 = (float)h[(size_t)i8 * DIM + lane];
            float v9 = (float)h[(size_t)i9 * DIM + lane];
            float vA = (float)h[(size_t)iA * DIM + lane];
            float vB = (float)h[(size_t)iB * DIM + lane];
            float vC = (float)h[(size_t)iC * DIM + lane];
            float vD = (float)h[(size_t)iD * DIM + lane];
            float vE = (float)h[(size_t)iE * DIM + lane];
            float vF = (float)h[(size_t)iF * DIM + lane];
            acc += (((v0 + v1) + (v2 + v3)) + ((v4 + v5) + (v6 + v7)))
                 + (((v8 + v9) + (vA + vB)) + ((vC + vD) + (vE + vF)));
        }
        S16[wave * 4 + rr][lane] = acc * invdeg[d];
    }
    __syncthreads();

    // ---------- phase B: root GEMM (K=64) + aggregate epilogue ----------
    int n = tile * 16 + l15;
    int nc = (n < N) ? n : (N - 1);
    const __bf16* xrow = xin + (size_t)nc * DIM + lg * 8;
    bf16x8 bv0 = *reinterpret_cast<const bf16x8*>(xrow);
    bf16x8 bv1 = *reinterpret_cast<const bf16x8*>(xrow + 32);
    f32x4 acc = (f32x4){0.f, 0.f, 0.f, 0.f};
    acc = __builtin_amdgcn_mfma_f32_16x16x32_bf16(ar0, bv0, acc, 0, 0, 0);
    acc = __builtin_amdgcn_mfma_f32_16x16x32_bf16(ar1, bv1, acc, 0, 0, 0);

    if (n < N) {
        f32x4 ag = *reinterpret_cast<const f32x4*>(&S16[l15][cbase]);
        bf16x4 hv;
#pragma unroll
        for (int i = 0; i < 4; ++i)
            hv[i] = (__bf16)fmaxf(acc[i] + ag[i] + bias4[i], 0.f);
        *reinterpret_cast<bf16x4*>(xout + (size_t)n * DIM + cbase) = hv;
    }
}

// ---------------- score ----------------
__global__ __launch_bounds__(256) void score_kernel(const __bf16* __restrict__ xb,
                                                    const int* __restrict__ s,
                                                    const int* __restrict__ t,
                                                    float* __restrict__ out, int T) {
    int i = blockIdx.x * 4 + (threadIdx.x >> 6);
    if (i >= T) return;
    int lane = threadIdx.x & 63;
    float p = (float)xb[(size_t)s[i] * DIM + lane] * (float)xb[(size_t)t[i] * DIM + lane];
#pragma unroll
    for (int off = 32; off > 0; off >>= 1) p += __shfl_down(p, off, 64);
    if (lane == 0) out[i] = p;
}

extern "C" void kernel_launch(void* const* d_in, const int* in_sizes, int n_in,
                              void* d_out, int out_size, void* d_ws, size_t ws_size,
                              hipStream_t stream) {
    const int*   x_idx  = (const int*)d_in[0];
    const int*   eidx   = (const int*)d_in[1];   // [2,E]
    const int*   etyp   = (const int*)d_in[2];   // [E]
    const int*   tidx   = (const int*)d_in[3];   // [2,T]
    const float* emb    = (const float*)d_in[4]; // [N,64]
    const float* weight = (const float*)d_in[5]; // [L,8,64,64]
    const float* root   = (const float*)d_in[6]; // [L,64,64]
    const float* bias   = (const float*)d_in[7]; // [L,64]

    int N = in_sizes[0];
    int E = in_sizes[2];
    int T = in_sizes[3] / 2;
    int L = in_sizes[5] / (NREL * DIM * DIM);

    const int* src = eidx;
    const int* dst = eidx + E;
    const int* ts  = tidx;
    const int* tt  = tidx + T;
    float* out = (float*)d_out;

    int epad_cap = E + 3 * N + 64;              // per-row pad <= 3, + 16-deep over-read slack

    // ---- workspace carve-up ----
    char* p = (char*)d_ws;
    auto alloc = [&](size_t bytes) -> void* {
        void* r = (void*)p;
        p += (bytes + 255) & ~(size_t)255;
        return r;
    };
    __bf16* hbuf    = (__bf16*)alloc(((size_t)N * NREL + 1) * DIM * sizeof(__bf16)); // +1 zero row
    __bf16* xb0     = (__bf16*)alloc((size_t)N * DIM * sizeof(__bf16));
    __bf16* xb1     = (__bf16*)alloc((size_t)N * DIM * sizeof(__bf16));
    __bf16* Wt2     = (__bf16*)alloc((size_t)L * KTOT * DIM * sizeof(__bf16));
    int*    srcs    = (int*)   alloc((size_t)epad_cap * sizeof(int));
    int*    eoff    = (int*)   alloc((size_t)E * sizeof(int));
    int*    deg8    = (int*)   alloc(((size_t)N * 8 + 8) * sizeof(int));  // +8: gtotal at [N*8]
    int*    rp      = (int*)   alloc((size_t)N * 8 * sizeof(int));
    int*    rend    = (int*)   alloc((size_t)N * sizeof(int));
    float*  invdeg  = (float*) alloc((size_t)N * sizeof(float));

    int* gtotal = deg8 + (size_t)N * 8;         // zeroed by the same memset

    int nb = (N + 255) / 256;
    int ntiles = (N + 15) / 16;

    hipMemsetAsync(deg8, 0, ((size_t)N * 8 + 8) * sizeof(int), stream);
    {   // grid must cover max(epad_cap, E, N*DIM/8, DIM)
        int work = epad_cap;
        if (E > work) work = E;
        int copyw = N * (DIM / 8);
        if (copyw > work) work = copyw;
        histgather_kernel<<<(work + 255) / 256, 256, 0, stream>>>(
            dst, etyp, deg8, eoff, x_idx, emb, xb0, hbuf, srcs, N, E, epad_cap);
    }
    scan1rp_kernel<<<nb, 256, 0, stream>>>(deg8, gtotal, invdeg, rp, rend,
                                           weight, root, Wt2, N, L);
    {
        int half = (E + 1) / 2;
        bucket_kernel<<<(half + 255) / 256, 256, 0, stream>>>(src, dst, etyp, rp, eoff, srcs, E);
    }

    __bf16* xcur = xb0;
    __bf16* xnxt = xb1;
    for (int l = 0; l < L; ++l) {
        transform_kernel<<<2048, 256, 0, stream>>>(xcur, Wt2 + (size_t)l * KTOT * DIM, hbuf, N);
        aggroot_kernel<<<ntiles, 256, 0, stream>>>(hbuf, xcur, srcs, rp, rend, invdeg,
                                                   Wt2 + (size_t)l * KTOT * DIM,
                                                   bias + (size_t)l * DIM,
                                                   xnxt, N);
        __bf16* tmp = xcur; xcur = xnxt; xnxt = tmp;
    }

    score_kernel<<<(T + 3) / 4, 256, 0, stream>>>(xcur, ts, tt, out, T);
}